// Round 10
// baseline (282.245 us; speedup 1.0000x reference)
//
#include <hip/hip_runtime.h>
#include <hip/hip_bf16.h>

#define B_ROWS 4096
#define T_LEN  8192
#define N_TAPS 256

typedef __attribute__((ext_vector_type(8))) short short8;
typedef __attribute__((ext_vector_type(4))) short short4v;
typedef __attribute__((ext_vector_type(4))) float f32x4;

__device__ inline ushort f2bf(float f) {
    __hip_bfloat16 h = __float2bfloat16(f);
    union { __hip_bfloat16 h; ushort u; } c;
    c.h = h;
    return c.u;
}

// async global->LDS, 16 B per lane. LDS dest = wave-uniform base + lane*16.
typedef __attribute__((address_space(1))) const void g_void;
typedef __attribute__((address_space(3))) void s_void;
__device__ inline void gload16(const void* g, void* s) {
    __builtin_amdgcn_global_load_lds((g_void*)g, (s_void*)s, 16, 0, 0);
}

// ---------------------------------------------------------------------------
// Phase 0a: cast z (256 x 8192 fp32) -> zbf (bf16)
// ---------------------------------------------------------------------------
__global__ __launch_bounds__(256) void fir_cast_z(const float* __restrict__ z,
                                                  ushort* __restrict__ zbf) {
    const int idx = (blockIdx.x * 256 + threadIdx.x) * 8;
    float4 a = *(const float4*)&z[idx];
    float4 b = *(const float4*)&z[idx + 4];
    short8 o;
    o[0] = (short)f2bf(a.x); o[1] = (short)f2bf(a.y);
    o[2] = (short)f2bf(a.z); o[3] = (short)f2bf(a.w);
    o[4] = (short)f2bf(b.x); o[5] = (short)f2bf(b.y);
    o[6] = (short)f2bf(b.z); o[7] = (short)f2bf(b.w);
    *(short8*)&zbf[idx] = o;
}

// ---------------------------------------------------------------------------
// Phase 0b: Toeplitz B-fragment table (unchanged, verified R3)
// ---------------------------------------------------------------------------
__global__ void fir_build_wtab(const float* __restrict__ b,
                               ushort* __restrict__ wtab) {
    const int a = blockIdx.x;        // 0..21
    const int lane = threadIdx.x;    // 0..63
    const int l15 = lane & 15, lg = lane >> 4;
    short8 o;
    #pragma unroll
    for (int j = 0; j < 8; ++j) {
        const int bi = 16 * a - 32 + l15 - lg * 8 - j;
        const float v = (bi >= 0 && bi < N_TAPS) ? b[bi] : 0.f;
        o[j] = (short)f2bf(v);
    }
    *(short8*)&wtab[(a * 64 + lane) * 8] = o;
}

// ---------------------------------------------------------------------------
// Phase 1: zi GEMM — T4 counted-vmcnt pipeline (never drain to 0 in loop).
// Little's-law diagnosis of R3-R9 (all ~80-100 µs): every variant drained
// vmcnt(0) at each barrier (__syncthreads), so loads were in flight only in
// short bursts -> ~1 TB/s regardless of pattern/occupancy. Fix: raw
// s_barrier + asm vmcnt(8): tile t+1's loads stay in flight across BOTH
// barriers (depth-2 prefetch, ~24 MB chip-wide in flight >> 5.7 MB needed).
//   iter t: {vmcnt(8); sbar; compute buf[t&1]; sbar; issue t+2 -> buf[t&1]}
// A staged fp32 (cvt at frag-read), B bf16; pre-swizzled src <-> XOR read
// (byte-identical math to verified R4/R7). MT=128, GBK=64, 512 thr, 8 waves.
// ---------------------------------------------------------------------------
#define MT 128
#define GBK 64

__global__ __launch_bounds__(512, 2) void fir_zi_gemm(
        const float* __restrict__ x,
        const ushort* __restrict__ zbf,
        float* __restrict__ part,
        int kslices) {
    __shared__ float  Asf[2][MT * GBK];      // 2 x 32 KB fp32 (128 rows x 256 B)
    __shared__ ushort Bs[2][N_TAPS * GBK];   // 2 x 32 KB bf16 (256 rows x 128 B)
    const int i0 = blockIdx.x * MT;
    const int ks = blockIdx.y;
    const int klen = T_LEN / kslices;        // 1024
    const int kbase = ks * klen;
    const int tid = threadIdx.x;
    const int wid = tid >> 6;                // 0..7
    const int lane = tid & 63;
    const int wm = wid >> 2, wn = wid & 3;
    const int l15 = lane & 15, lg = lane >> 4;

    f32x4 acc[4][4];
    #pragma unroll
    for (int mi = 0; mi < 4; ++mi)
        #pragma unroll
        for (int ni = 0; ni < 4; ++ni) acc[mi][ni] = (f32x4){0.f, 0.f, 0.f, 0.f};

    const int nt = klen / GBK;               // 16

    // 8 gload_lds per thread per tile (A:4 + B:4) -> vmcnt unit = 8
    auto stage = [&](int t, int buf) {
        const int kc = kbase + t * GBK;
        #pragma unroll
        for (int q = 0; q < 4; ++q) {        // A: 32 segs x 1 KB (4 rows each)
            const int seg = q * 8 + wid;
            const int row = seg * 4 + (lane >> 4);          // 0..127
            const int sc  = (lane & 15) ^ (row & 7);        // pre-swizzled src
            gload16(&x[(size_t)(i0 + row) * T_LEN + kc + sc * 4],
                    (char*)Asf[buf] + seg * 1024);
        }
        #pragma unroll
        for (int q = 0; q < 4; ++q) {        // B: 32 segs x 1 KB (8 rows each)
            const int seg = wid * 4 + q;
            const int row = seg * 8 + (lane >> 3);          // 0..255
            const int sc  = (lane & 7) ^ (row & 7);
            gload16(&zbf[(size_t)row * T_LEN + kc + sc * 8],
                    (char*)Bs[buf] + seg * 1024);
        }
    };

    stage(0, 0);
    stage(1, 1);

    for (int t = 0; t < nt; ++t) {
        const int cb = t & 1;
        if (t + 1 < nt) {
            asm volatile("s_waitcnt vmcnt(8)" ::: "memory");   // tile t done,
        } else {                                               // t+1 in flight
            asm volatile("s_waitcnt vmcnt(0)" ::: "memory");
        }
        __builtin_amdgcn_sched_barrier(0);
        __builtin_amdgcn_s_barrier();
        __builtin_amdgcn_sched_barrier(0);

        #pragma unroll
        for (int ksb = 0; ksb < 2; ++ksb) {
            short8 af[4], bfr[4];
            #pragma unroll
            for (int mi = 0; mi < 4; ++mi) {
                const int row = wm * 64 + mi * 16 + l15;
                const int c0 = ksb * 8 + lg * 2;             // 16B chunks
                const f32x4 v0 = *(const f32x4*)((const char*)Asf[cb] + row * 256
                                                 + ((c0 ^ (row & 7)) * 16));
                const f32x4 v1 = *(const f32x4*)((const char*)Asf[cb] + row * 256
                                                 + (((c0 + 1) ^ (row & 7)) * 16));
                short8 f;
                f[0] = (short)f2bf(v0[0]); f[1] = (short)f2bf(v0[1]);
                f[2] = (short)f2bf(v0[2]); f[3] = (short)f2bf(v0[3]);
                f[4] = (short)f2bf(v1[0]); f[5] = (short)f2bf(v1[1]);
                f[6] = (short)f2bf(v1[2]); f[7] = (short)f2bf(v1[3]);
                af[mi] = f;
            }
            #pragma unroll
            for (int ni = 0; ni < 4; ++ni) {
                const int row = wn * 64 + ni * 16 + l15;
                const int c = lg + ksb * 4;
                bfr[ni] = *(const short8*)((const char*)Bs[cb] + row * 128
                                           + ((c ^ (row & 7)) << 4));
            }
            #pragma unroll
            for (int mi = 0; mi < 4; ++mi)
                #pragma unroll
                for (int ni = 0; ni < 4; ++ni)
                    acc[mi][ni] = __builtin_amdgcn_mfma_f32_16x16x32_bf16(
                        af[mi], bfr[ni], acc[mi][ni], 0, 0, 0);
        }

        __builtin_amdgcn_sched_barrier(0);
        __builtin_amdgcn_s_barrier();        // all reads of buf cb done
        __builtin_amdgcn_sched_barrier(0);
        if (t + 2 < nt) stage(t + 2, cb);    // overwrite cb; rides ahead
    }

    // C/D layout: col = lane&15, row = (lane>>4)*4 + reg
    #pragma unroll
    for (int mi = 0; mi < 4; ++mi) {
        #pragma unroll
        for (int ni = 0; ni < 4; ++ni) {
            const int gn = wn * 64 + ni * 16 + l15;
            #pragma unroll
            for (int rg = 0; rg < 4; ++rg) {
                const int gm = i0 + wm * 64 + mi * 16 + lg * 4 + rg;
                part[((size_t)ks * B_ROWS + gm) * N_TAPS + gn] = acc[mi][ni][rg];
            }
        }
    }
}

// ---------------------------------------------------------------------------
// Phase 3: FIR conv via MFMA. Halo now sums split-K partials directly
// (fir_zi_reduce deleted): zi[i][j] = sum_q part[q][i][j]. Only the
// blockIdx.x==0 column (256 of 2048 blocks) takes this path.
// ---------------------------------------------------------------------------
#define VBM 16
#define VBT 1024
#define VSTR 2560

__global__ __launch_bounds__(256, 2) void fir_conv_mfma(
        const float* __restrict__ x,
        const ushort* __restrict__ wtab,
        const float* __restrict__ part,
        int kslices,
        float* __restrict__ y) {
    __shared__ ushort xe[VBM * VSTR / 2];
    const int t0 = blockIdx.x * VBT;
    const int i0 = blockIdx.y * VBM;
    const int tid = threadIdx.x;
    const int lane = tid & 63, wid = tid >> 6;
    const int l15 = lane & 15, lg = lane >> 4;

    short8 wf[18];
    #pragma unroll
    for (int a = 0; a < 18; ++a)
        wf[a] = *(const short8*)&wtab[((a + 2) * 64 + lane) * 8];

    #pragma unroll
    for (int it = 0; it < 8; ++it) {
        const int e = tid + it * 256;
        const int r = e >> 7;
        const int c8 = e & 127;
        const int g = t0 + c8 * 8;
        float4 v0 = *(const float4*)&x[(size_t)(i0 + r) * T_LEN + g];
        float4 v1 = *(const float4*)&x[(size_t)(i0 + r) * T_LEN + g + 4];
        short8 o;
        o[0] = (short)f2bf(v0.x); o[1] = (short)f2bf(v0.y);
        o[2] = (short)f2bf(v0.z); o[3] = (short)f2bf(v0.w);
        o[4] = (short)f2bf(v1.x); o[5] = (short)f2bf(v1.y);
        o[6] = (short)f2bf(v1.z); o[7] = (short)f2bf(v1.w);
        const int off = (512 + c8 * 16) ^ ((r & 7) << 4);
        *(short8*)((char*)xe + r * VSTR + off) = o;
    }
    #pragma unroll
    for (int it = 0; it < 2; ++it) {
        const int e = tid + it * 256;
        const int r = e >> 5;
        const int c8 = e & 31;
        const int g = t0 - 256 + c8 * 8;
        short8 o;
        if (g >= 0) {
            float4 v0 = *(const float4*)&x[(size_t)(i0 + r) * T_LEN + g];
            float4 v1 = *(const float4*)&x[(size_t)(i0 + r) * T_LEN + g + 4];
            o[0] = (short)f2bf(v0.x); o[1] = (short)f2bf(v0.y);
            o[2] = (short)f2bf(v0.z); o[3] = (short)f2bf(v0.w);
            o[4] = (short)f2bf(v1.x); o[5] = (short)f2bf(v1.y);
            o[6] = (short)f2bf(v1.z); o[7] = (short)f2bf(v1.w);
        } else {
            #pragma unroll
            for (int jj = 0; jj < 8; ++jj) {
                const int zidx = -1 - g - jj;          // 0..255
                float s = 0.f;
                for (int q = 0; q < kslices; ++q)
                    s += part[((size_t)q * B_ROWS + (i0 + r)) * N_TAPS + zidx];
                o[jj] = (short)f2bf(s);
            }
        }
        const int off = (c8 * 16) ^ ((r & 7) << 4);
        *(short8*)((char*)xe + r * VSTR + off) = o;
    }
    __syncthreads();

    f32x4 acc[4][4];
    #pragma unroll
    for (int c4 = 0; c4 < 4; ++c4)
        #pragma unroll
        for (int n = 0; n < 4; ++n) acc[c4][n] = (f32x4){0.f, 0.f, 0.f, 0.f};

    const int chunk0 = wid * 4;
    #pragma unroll
    for (int ui = 0; ui < 10; ++ui) {
        #pragma unroll
        for (int c4 = 0; c4 < 4; ++c4) {
            const int colw = (chunk0 + c4) * 64 + ui * 32 + lg * 8;
            const int off = (colw * 2) ^ ((l15 & 7) << 4);
            short8 af = *(const short8*)((const char*)xe + l15 * VSTR + off);
            #pragma unroll
            for (int ncol = 0; ncol < 4; ++ncol) {
                const int a = ncol + 18 - 2 * ui;
                if (a >= 2 && a <= 19)
                    acc[c4][ncol] = __builtin_amdgcn_mfma_f32_16x16x32_bf16(
                        af, wf[a - 2], acc[c4][ncol], 0, 0, 0);
            }
        }
    }

    #pragma unroll
    for (int c4 = 0; c4 < 4; ++c4) {
        #pragma unroll
        for (int ncol = 0; ncol < 4; ++ncol) {
            const size_t tcol = (size_t)t0 + (chunk0 + c4) * 64 + ncol * 16 + l15;
            #pragma unroll
            for (int rg = 0; rg < 4; ++rg) {
                y[(size_t)(i0 + lg * 4 + rg) * T_LEN + tcol] = acc[c4][ncol][rg];
            }
        }
    }
}

// ---------------------------------------------------------------------------
extern "C" void kernel_launch(void* const* d_in, const int* in_sizes, int n_in,
                              void* d_out, int out_size, void* d_ws, size_t ws_size,
                              hipStream_t stream) {
    const float* x  = (const float*)d_in[0];
    const float* b  = (const float*)d_in[1];
    const float* z  = (const float*)d_in[2];
    float* y = (float*)d_out;

    char* ws = (char*)d_ws;
    ushort* zbf  = (ushort*)(ws + (4u << 20));            // 4 MB
    ushort* wtab = (ushort*)(ws + (8u << 20));            // 22.5 KB (reserve 64K)
    float*  part = (float*)(ws + (8u << 20) + (64u << 10));

    int kslices = 8;
    while (kslices > 1 &&
           (size_t)(8u << 20) + (64u << 10) + (size_t)kslices * (4u << 20) > ws_size)
        kslices >>= 1;

    fir_build_wtab<<<22, 64, 0, stream>>>(b, wtab);
    fir_cast_z<<<N_TAPS * T_LEN / (256 * 8), 256, 0, stream>>>(z, zbf);

    dim3 ggrid(B_ROWS / MT, kslices);                     // 32 x 8 = 256 blocks
    fir_zi_gemm<<<ggrid, 512, 0, stream>>>(x, zbf, part, kslices);

    dim3 cgrid(T_LEN / VBT, B_ROWS / VBM);                // 8 x 256
    fir_conv_mfma<<<cgrid, 256, 0, stream>>>(x, wtab, part, kslices, y);
}

// Round 11
// 108.333 us; speedup vs baseline: 2.6053x; 2.6053x over previous
//
#include <hip/hip_runtime.h>
#include <hip/hip_bf16.h>

#define B_ROWS 4096
#define T_LEN  8192
#define N_TAPS 256

typedef __attribute__((ext_vector_type(8))) short short8;
typedef __attribute__((ext_vector_type(4))) short short4v;
typedef __attribute__((ext_vector_type(4))) float f32x4;

__device__ inline ushort f2bf(float f) {
    __hip_bfloat16 h = __float2bfloat16(f);
    union { __hip_bfloat16 h; ushort u; } c;
    c.h = h;
    return c.u;
}

// async global->LDS, 16 B per lane. LDS dest = wave-uniform base + lane*16.
typedef __attribute__((address_space(1))) const void g_void;
typedef __attribute__((address_space(3))) void s_void;
__device__ inline void gload16(const void* g, void* s) {
    __builtin_amdgcn_global_load_lds((g_void*)g, (s_void*)s, 16, 0, 0);
}

// ---------------------------------------------------------------------------
// Phase 0a: cast z (256 x 8192 fp32) -> zbf (bf16)
// ---------------------------------------------------------------------------
__global__ __launch_bounds__(256) void fir_cast_z(const float* __restrict__ z,
                                                  ushort* __restrict__ zbf) {
    const int idx = (blockIdx.x * 256 + threadIdx.x) * 8;
    float4 a = *(const float4*)&z[idx];
    float4 b = *(const float4*)&z[idx + 4];
    short8 o;
    o[0] = (short)f2bf(a.x); o[1] = (short)f2bf(a.y);
    o[2] = (short)f2bf(a.z); o[3] = (short)f2bf(a.w);
    o[4] = (short)f2bf(b.x); o[5] = (short)f2bf(b.y);
    o[6] = (short)f2bf(b.z); o[7] = (short)f2bf(b.w);
    *(short8*)&zbf[idx] = o;
}

// ---------------------------------------------------------------------------
// Phase 0b: Toeplitz B-fragment table (unchanged, verified R3)
// ---------------------------------------------------------------------------
__global__ void fir_build_wtab(const float* __restrict__ b,
                               ushort* __restrict__ wtab) {
    const int a = blockIdx.x;        // 0..21
    const int lane = threadIdx.x;    // 0..63
    const int l15 = lane & 15, lg = lane >> 4;
    short8 o;
    #pragma unroll
    for (int j = 0; j < 8; ++j) {
        const int bi = 16 * a - 32 + l15 - lg * 8 - j;
        const float v = (bi >= 0 && bi < N_TAPS) ? b[bi] : 0.f;
        o[j] = (short)f2bf(v);
    }
    *(short8*)&wtab[(a * 64 + lane) * 8] = o;
}

// ---------------------------------------------------------------------------
// Phase 1: zi GEMM — T4 counted-vmcnt pipeline (R10, measured ~40 µs; the
// 83->40 win). Never drain vmcnt to 0 in the loop: tile t+1's 8 gload_lds
// ride across both barriers (depth-2 prefetch). UNCHANGED from R10.
// ---------------------------------------------------------------------------
#define MT 128
#define GBK 64

__global__ __launch_bounds__(512, 2) void fir_zi_gemm(
        const float* __restrict__ x,
        const ushort* __restrict__ zbf,
        float* __restrict__ part,
        int kslices) {
    __shared__ float  Asf[2][MT * GBK];      // 2 x 32 KB fp32 (128 rows x 256 B)
    __shared__ ushort Bs[2][N_TAPS * GBK];   // 2 x 32 KB bf16 (256 rows x 128 B)
    const int i0 = blockIdx.x * MT;
    const int ks = blockIdx.y;
    const int klen = T_LEN / kslices;        // 1024
    const int kbase = ks * klen;
    const int tid = threadIdx.x;
    const int wid = tid >> 6;                // 0..7
    const int lane = tid & 63;
    const int wm = wid >> 2, wn = wid & 3;
    const int l15 = lane & 15, lg = lane >> 4;

    f32x4 acc[4][4];
    #pragma unroll
    for (int mi = 0; mi < 4; ++mi)
        #pragma unroll
        for (int ni = 0; ni < 4; ++ni) acc[mi][ni] = (f32x4){0.f, 0.f, 0.f, 0.f};

    const int nt = klen / GBK;               // 16

    // 8 gload_lds per thread per tile (A:4 + B:4) -> vmcnt unit = 8
    auto stage = [&](int t, int buf) {
        const int kc = kbase + t * GBK;
        #pragma unroll
        for (int q = 0; q < 4; ++q) {        // A: 32 segs x 1 KB (4 rows each)
            const int seg = q * 8 + wid;
            const int row = seg * 4 + (lane >> 4);          // 0..127
            const int sc  = (lane & 15) ^ (row & 7);        // pre-swizzled src
            gload16(&x[(size_t)(i0 + row) * T_LEN + kc + sc * 4],
                    (char*)Asf[buf] + seg * 1024);
        }
        #pragma unroll
        for (int q = 0; q < 4; ++q) {        // B: 32 segs x 1 KB (8 rows each)
            const int seg = wid * 4 + q;
            const int row = seg * 8 + (lane >> 3);          // 0..255
            const int sc  = (lane & 7) ^ (row & 7);
            gload16(&zbf[(size_t)row * T_LEN + kc + sc * 8],
                    (char*)Bs[buf] + seg * 1024);
        }
    };

    stage(0, 0);
    stage(1, 1);

    for (int t = 0; t < nt; ++t) {
        const int cb = t & 1;
        if (t + 1 < nt) {
            asm volatile("s_waitcnt vmcnt(8)" ::: "memory");   // tile t done,
        } else {                                               // t+1 in flight
            asm volatile("s_waitcnt vmcnt(0)" ::: "memory");
        }
        __builtin_amdgcn_sched_barrier(0);
        __builtin_amdgcn_s_barrier();
        __builtin_amdgcn_sched_barrier(0);

        #pragma unroll
        for (int ksb = 0; ksb < 2; ++ksb) {
            short8 af[4], bfr[4];
            #pragma unroll
            for (int mi = 0; mi < 4; ++mi) {
                const int row = wm * 64 + mi * 16 + l15;
                const int c0 = ksb * 8 + lg * 2;             // 16B chunks
                const f32x4 v0 = *(const f32x4*)((const char*)Asf[cb] + row * 256
                                                 + ((c0 ^ (row & 7)) * 16));
                const f32x4 v1 = *(const f32x4*)((const char*)Asf[cb] + row * 256
                                                 + (((c0 + 1) ^ (row & 7)) * 16));
                short8 f;
                f[0] = (short)f2bf(v0[0]); f[1] = (short)f2bf(v0[1]);
                f[2] = (short)f2bf(v0[2]); f[3] = (short)f2bf(v0[3]);
                f[4] = (short)f2bf(v1[0]); f[5] = (short)f2bf(v1[1]);
                f[6] = (short)f2bf(v1[2]); f[7] = (short)f2bf(v1[3]);
                af[mi] = f;
            }
            #pragma unroll
            for (int ni = 0; ni < 4; ++ni) {
                const int row = wn * 64 + ni * 16 + l15;
                const int c = lg + ksb * 4;
                bfr[ni] = *(const short8*)((const char*)Bs[cb] + row * 128
                                           + ((c ^ (row & 7)) << 4));
            }
            #pragma unroll
            for (int mi = 0; mi < 4; ++mi)
                #pragma unroll
                for (int ni = 0; ni < 4; ++ni)
                    acc[mi][ni] = __builtin_amdgcn_mfma_f32_16x16x32_bf16(
                        af[mi], bfr[ni], acc[mi][ni], 0, 0, 0);
        }

        __builtin_amdgcn_sched_barrier(0);
        __builtin_amdgcn_s_barrier();        // all reads of buf cb done
        __builtin_amdgcn_sched_barrier(0);
        if (t + 2 < nt) stage(t + 2, cb);    // overwrite cb; rides ahead
    }

    // C/D layout: col = lane&15, row = (lane>>4)*4 + reg
    #pragma unroll
    for (int mi = 0; mi < 4; ++mi) {
        #pragma unroll
        for (int ni = 0; ni < 4; ++ni) {
            const int gn = wn * 64 + ni * 16 + l15;
            #pragma unroll
            for (int rg = 0; rg < 4; ++rg) {
                const int gm = i0 + wm * 64 + mi * 16 + lg * 4 + rg;
                part[((size_t)ks * B_ROWS + gm) * N_TAPS + gn] = acc[mi][ni][rg];
            }
        }
    }
}

// ---------------------------------------------------------------------------
// Phase 2: reduce split-K partials -> zi (restored — R3-verified form)
// ---------------------------------------------------------------------------
__global__ __launch_bounds__(256) void fir_zi_reduce(const float* __restrict__ part,
                                                     float* __restrict__ zi,
                                                     int kslices) {
    const int idx = blockIdx.x * 256 + threadIdx.x;
    const int total = B_ROWS * N_TAPS / 4;
    if (idx >= total) return;
    float4 s = ((const float4*)part)[idx];
    for (int q = 1; q < kslices; ++q) {
        float4 v = ((const float4*)part)[(size_t)q * total + idx];
        s.x += v.x; s.y += v.y; s.z += v.z; s.w += v.w;
    }
    ((float4*)zi)[idx] = s;
}

// ---------------------------------------------------------------------------
// Phase 3: FIR conv via MFMA — EXACT R3 form (zi input; proven ~20 µs and
// codegen-robust across six TUs R3-R9; the R10 part/kslices halo variant
// regressed it 10x and is reverted).
// ---------------------------------------------------------------------------
#define VBM 16
#define VBT 1024
#define VSTR 2560

__global__ __launch_bounds__(256, 2) void fir_conv_mfma(
        const float* __restrict__ x,
        const ushort* __restrict__ wtab,
        const float* __restrict__ zi,
        float* __restrict__ y) {
    __shared__ ushort xe[VBM * VSTR / 2];
    const int t0 = blockIdx.x * VBT;
    const int i0 = blockIdx.y * VBM;
    const int tid = threadIdx.x;
    const int lane = tid & 63, wid = tid >> 6;
    const int l15 = lane & 15, lg = lane >> 4;

    short8 wf[18];
    #pragma unroll
    for (int a = 0; a < 18; ++a)
        wf[a] = *(const short8*)&wtab[((a + 2) * 64 + lane) * 8];

    #pragma unroll
    for (int it = 0; it < 8; ++it) {
        const int e = tid + it * 256;
        const int r = e >> 7;
        const int c8 = e & 127;
        const int g = t0 + c8 * 8;
        float4 v0 = *(const float4*)&x[(size_t)(i0 + r) * T_LEN + g];
        float4 v1 = *(const float4*)&x[(size_t)(i0 + r) * T_LEN + g + 4];
        short8 o;
        o[0] = (short)f2bf(v0.x); o[1] = (short)f2bf(v0.y);
        o[2] = (short)f2bf(v0.z); o[3] = (short)f2bf(v0.w);
        o[4] = (short)f2bf(v1.x); o[5] = (short)f2bf(v1.y);
        o[6] = (short)f2bf(v1.z); o[7] = (short)f2bf(v1.w);
        const int off = (512 + c8 * 16) ^ ((r & 7) << 4);
        *(short8*)((char*)xe + r * VSTR + off) = o;
    }
    #pragma unroll
    for (int it = 0; it < 2; ++it) {
        const int e = tid + it * 256;
        const int r = e >> 5;
        const int c8 = e & 31;
        const int g = t0 - 256 + c8 * 8;
        short8 o;
        if (g >= 0) {
            float4 v0 = *(const float4*)&x[(size_t)(i0 + r) * T_LEN + g];
            float4 v1 = *(const float4*)&x[(size_t)(i0 + r) * T_LEN + g + 4];
            o[0] = (short)f2bf(v0.x); o[1] = (short)f2bf(v0.y);
            o[2] = (short)f2bf(v0.z); o[3] = (short)f2bf(v0.w);
            o[4] = (short)f2bf(v1.x); o[5] = (short)f2bf(v1.y);
            o[6] = (short)f2bf(v1.z); o[7] = (short)f2bf(v1.w);
        } else {
            #pragma unroll
            for (int jj = 0; jj < 8; ++jj)
                o[jj] = (short)f2bf(zi[(size_t)(i0 + r) * N_TAPS + (-1 - g - jj)]);
        }
        const int off = (c8 * 16) ^ ((r & 7) << 4);
        *(short8*)((char*)xe + r * VSTR + off) = o;
    }
    __syncthreads();

    f32x4 acc[4][4];
    #pragma unroll
    for (int c4 = 0; c4 < 4; ++c4)
        #pragma unroll
        for (int n = 0; n < 4; ++n) acc[c4][n] = (f32x4){0.f, 0.f, 0.f, 0.f};

    const int chunk0 = wid * 4;
    #pragma unroll
    for (int ui = 0; ui < 10; ++ui) {
        #pragma unroll
        for (int c4 = 0; c4 < 4; ++c4) {
            const int colw = (chunk0 + c4) * 64 + ui * 32 + lg * 8;
            const int off = (colw * 2) ^ ((l15 & 7) << 4);
            short8 af = *(const short8*)((const char*)xe + l15 * VSTR + off);
            #pragma unroll
            for (int ncol = 0; ncol < 4; ++ncol) {
                const int a = ncol + 18 - 2 * ui;
                if (a >= 2 && a <= 19)
                    acc[c4][ncol] = __builtin_amdgcn_mfma_f32_16x16x32_bf16(
                        af, wf[a - 2], acc[c4][ncol], 0, 0, 0);
            }
        }
    }

    #pragma unroll
    for (int c4 = 0; c4 < 4; ++c4) {
        #pragma unroll
        for (int ncol = 0; ncol < 4; ++ncol) {
            const size_t tcol = (size_t)t0 + (chunk0 + c4) * 64 + ncol * 16 + l15;
            #pragma unroll
            for (int rg = 0; rg < 4; ++rg) {
                y[(size_t)(i0 + lg * 4 + rg) * T_LEN + tcol] = acc[c4][ncol][rg];
            }
        }
    }
}

// ---------------------------------------------------------------------------
extern "C" void kernel_launch(void* const* d_in, const int* in_sizes, int n_in,
                              void* d_out, int out_size, void* d_ws, size_t ws_size,
                              hipStream_t stream) {
    const float* x  = (const float*)d_in[0];
    const float* b  = (const float*)d_in[1];
    const float* z  = (const float*)d_in[2];
    float* y = (float*)d_out;

    char* ws = (char*)d_ws;
    float*  zi   = (float*)ws;                            // 4 MB
    ushort* zbf  = (ushort*)(ws + (4u << 20));            // 4 MB
    ushort* wtab = (ushort*)(ws + (8u << 20));            // 22.5 KB (reserve 64K)
    float*  part = (float*)(ws + (8u << 20) + (64u << 10));

    int kslices = 8;
    while (kslices > 1 &&
           (size_t)(8u << 20) + (64u << 10) + (size_t)kslices * (4u << 20) > ws_size)
        kslices >>= 1;

    fir_build_wtab<<<22, 64, 0, stream>>>(b, wtab);
    fir_cast_z<<<N_TAPS * T_LEN / (256 * 8), 256, 0, stream>>>(z, zbf);

    dim3 ggrid(B_ROWS / MT, kslices);                     // 32 x 8 = 256 blocks
    fir_zi_gemm<<<ggrid, 512, 0, stream>>>(x, zbf, part, kslices);

    fir_zi_reduce<<<B_ROWS * N_TAPS / 4 / 256, 256, 0, stream>>>(part, zi, kslices);

    dim3 cgrid(T_LEN / VBT, B_ROWS / VBM);                // 8 x 256
    fir_conv_mfma<<<cgrid, 256, 0, stream>>>(x, wtab, zi, y);
}